// Round 10
// baseline (558.855 us; speedup 1.0000x reference)
//
#include <hip/hip_runtime.h>

#define N_USERS 100000
#define N_ITEMS 50000
#define N_NODES 150000
#define NNZ     2400000
#define EMB     64
#define NLAYERS 3
#define BATCH   16384
#define REG     1e-5f

#define SCAN_BS    256
#define SCAN_ELEMS 8
#define SCAN_CHUNK (SCAN_BS * SCAN_ELEMS)   // 2048
#define SCAN_NB    ((N_NODES + SCAN_CHUNK - 1) / SCAN_CHUNK)  // 74

#define NTILES ((N_NODES + 63) / 64)  // 2344

#define ROWS_PER_BUCKET 256
#define NB_BUCKET ((N_NODES + ROWS_PER_BUCKET - 1) / ROWS_PER_BUCKET)  // 586
#define BIN_CHUNK 8192
#define BIN_NB ((NNZ + BIN_CHUNK - 1) / BIN_CHUNK)  // 293

typedef __attribute__((ext_vector_type(8))) short bfrag8;  // 8 bf16 (4 VGPRs)
typedef __attribute__((ext_vector_type(4))) float vf4;     // 4 f32 acc

__device__ inline unsigned short f2bf(float x) {  // f32 -> bf16 RTN-even
    unsigned int u = __builtin_bit_cast(unsigned int, x);
    return (unsigned short)((u + 0x7fffu + ((u >> 16) & 1u)) >> 16);
}
__device__ inline float bf2f(unsigned short h) {
    unsigned int u = ((unsigned int)h) << 16;
    return __builtin_bit_cast(float, u);
}

// ---------------- init: ego_bf = bf16(concat(user_emb, item_emb)) -------
__global__ void init_ego_kernel(const float4* __restrict__ ue,
                                const float4* __restrict__ ie,
                                ushort4* __restrict__ ego_bf) {
    const int n4u = N_USERS * (EMB / 4);
    const int n4  = N_NODES * (EMB / 4);
    for (int t = blockIdx.x * blockDim.x + threadIdx.x; t < n4;
         t += gridDim.x * blockDim.x) {
        float4 v = (t < n4u) ? ue[t] : ie[t - n4u];
        ushort4 h;
        h.x = f2bf(v.x); h.y = f2bf(v.y); h.z = f2bf(v.z); h.w = f2bf(v.w);
        ego_bf[t] = h;
    }
}

// ---------------- prep: BT[layer][j][k] = bf16([W1;W2][k][j]) ------------
__global__ __launch_bounds__(256) void prep_w_kernel(
    const float* __restrict__ W1, const float* __restrict__ W2,
    unsigned short* __restrict__ BT) {
    int idx = blockIdx.x * blockDim.x + threadIdx.x;
    if (idx >= NLAYERS * 64 * 128) return;
    int l = idx / 8192;
    int rem = idx - l * 8192;
    int j = rem >> 7;        // output dim (row of BT)
    int k = rem & 127;       // concat-K
    float w = (k < 64) ? W1[l * 4096 + k * 64 + j]
                       : W2[l * 4096 + (k - 64) * 64 + j];
    BT[idx] = f2bf(w);
}

// ---------------- counting sort: histogram ----------------
__global__ __launch_bounds__(256) void hist_kernel(const int* __restrict__ row,
                                                   int* __restrict__ cnt) {
    int e = blockIdx.x * blockDim.x + threadIdx.x;
    if (e < NNZ) atomicAdd(&cnt[row[e]], 1);
}

// ---------------- scan stage 1 ----------------
__global__ __launch_bounds__(SCAN_BS) void scan1_kernel(
    const int* __restrict__ cnt, int* __restrict__ rp, int* __restrict__ bsum) {
    __shared__ int lds[SCAN_BS];
    const int t = threadIdx.x;
    const int base = blockIdx.x * SCAN_CHUNK + t * SCAN_ELEMS;
    int vals[SCAN_ELEMS];
    int tsum = 0;
#pragma unroll
    for (int i = 0; i < SCAN_ELEMS; ++i) {
        int idx = base + i;
        vals[i] = (idx < N_NODES) ? cnt[idx] : 0;
        tsum += vals[i];
    }
    lds[t] = tsum;
    __syncthreads();
    int x = tsum;
    for (int off = 1; off < SCAN_BS; off <<= 1) {
        int y = (t >= off) ? lds[t - off] : 0;
        __syncthreads();
        x += y;
        lds[t] = x;
        __syncthreads();
    }
    int run = x - tsum;
#pragma unroll
    for (int i = 0; i < SCAN_ELEMS; ++i) {
        int idx = base + i;
        if (idx < N_NODES) rp[idx] = run;
        run += vals[i];
    }
    if (t == SCAN_BS - 1) bsum[blockIdx.x] = x;
}

// ---------------- scan stage 2 ----------------
__global__ __launch_bounds__(128) void scan2_kernel(int* __restrict__ bsum) {
    __shared__ int lds[128];
    const int t = threadIdx.x;
    int orig = (t < SCAN_NB) ? bsum[t] : 0;
    lds[t] = orig;
    __syncthreads();
    int x = orig;
    for (int off = 1; off < 128; off <<= 1) {
        int y = (t >= off) ? lds[t - off] : 0;
        __syncthreads();
        x += y;
        lds[t] = x;
        __syncthreads();
    }
    if (t < SCAN_NB) bsum[t] = x - orig;
}

// ---------------- scan stage 3: finalize rp, init bucket cursors --------
__global__ __launch_bounds__(256) void scan3_kernel(
    int* __restrict__ rp, const int* __restrict__ bsum,
    int* __restrict__ bucket_cursor) {
    int idx = blockIdx.x * blockDim.x + threadIdx.x;
    if (idx < N_NODES) {
        int v = rp[idx] + bsum[idx / SCAN_CHUNK];
        rp[idx] = v;
        if ((idx & (ROWS_PER_BUCKET - 1)) == 0)
            bucket_cursor[idx >> 8] = v;
    }
    if (idx == 0) rp[N_NODES] = NNZ;
}

// ---------------- pass A: bucket-binned scatter ----------------
__global__ __launch_bounds__(256) void binscatter_kernel(
    const int* __restrict__ row, const int* __restrict__ col,
    const float* __restrict__ val, int* __restrict__ bucket_cursor,
    int2* __restrict__ stage) {
    __shared__ int hist[NB_BUCKET];
    __shared__ int wbase[NB_BUCKET];
    const int t = threadIdx.x;
    const int s = blockIdx.x * BIN_CHUNK;
    const int e = min(s + BIN_CHUNK, NNZ);

    for (int b = t; b < NB_BUCKET; b += 256) hist[b] = 0;
    __syncthreads();
    for (int i = s + t; i < e; i += 256)
        atomicAdd(&hist[row[i] >> 8], 1);
    __syncthreads();
    for (int b = t; b < NB_BUCKET; b += 256) {
        int c = hist[b];
        wbase[b] = c ? atomicAdd(&bucket_cursor[b], c) : 0;
        hist[b] = 0;  // reuse as local cursor
    }
    __syncthreads();
    for (int i = s + t; i < e; i += 256) {
        int r = row[i];
        int b = r >> 8;
        int off = atomicAdd(&hist[b], 1);
        stage[wbase[b] + off] =
            make_int2(col[i] | ((r & 255) << 18),
                      __builtin_bit_cast(int, val[i]));
    }
}

// ---------------- pass B: per-bucket exact CSR placement ----------------
__global__ __launch_bounds__(256) void bucket_place_kernel(
    const int2* __restrict__ stage, const int* __restrict__ rp,
    int2* __restrict__ sce) {
    __shared__ int cur[ROWS_PER_BUCKET];
    const int b = blockIdx.x;
    const int t = threadIdx.x;
    const int row0 = b * ROWS_PER_BUCKET;
    const int row1 = min(row0 + ROWS_PER_BUCKET, N_NODES);
    int r = row0 + t;
    if (r < row1) cur[t] = rp[r];
    __syncthreads();
    const int B0 = rp[row0];
    const int B1 = rp[row1];
    for (int i = B0 + t; i < B1; i += 256) {
        int2 pk = stage[i];
        int rl = (pk.x >> 18) & 255;
        int pos = atomicAdd(&cur[rl], 1);
        sce[pos] = make_int2(pk.x & 0x3FFFF, pk.y);
    }
}

// ---------------- CSR SpMM: half-wave per edge, 2 dims/lane -------------
// One wave per row. Lanes 0-31 read edge A's full ego row (32 x 4B = 128B),
// lanes 32-63 edge B's => one gather instruction covers 2 edges. 16 edges
// in flight per 8 load slots. Halves combine via shfl_xor(32).
__global__ __launch_bounds__(256) void spmm_csr_kernel(
    const int* __restrict__ rp, const int2* __restrict__ sce,
    const unsigned short* __restrict__ ego_bf,
    unsigned short* __restrict__ side_bf) {
    const int lane = threadIdx.x & 63;
    const int half = lane >> 5;   // which edge of the pair
    const int sl   = lane & 31;   // dim-pair index (dims 2*sl, 2*sl+1)
    int r = (blockIdx.x * blockDim.x + threadIdx.x) >> 6;
    if (r >= N_NODES) return;
    const unsigned* egoU = (const unsigned*)ego_bf;  // row stride 32 uints
    int s = rp[r], e = rp[r + 1];
    float l0 = 0.f, l1 = 0.f, l2 = 0.f, l3 = 0.f;
    float h0 = 0.f, h1 = 0.f, h2 = 0.f, h3 = 0.f;
    int k = s;
    for (; k + 15 < e; k += 16) {
        int2 c0 = sce[k + 0 + half];
        int2 c1 = sce[k + 2 + half];
        int2 c2 = sce[k + 4 + half];
        int2 c3 = sce[k + 6 + half];
        int2 c4 = sce[k + 8 + half];
        int2 c5 = sce[k + 10 + half];
        int2 c6 = sce[k + 12 + half];
        int2 c7 = sce[k + 14 + half];
        unsigned g0 = egoU[(size_t)c0.x * 32 + sl];
        unsigned g1 = egoU[(size_t)c1.x * 32 + sl];
        unsigned g2 = egoU[(size_t)c2.x * 32 + sl];
        unsigned g3 = egoU[(size_t)c3.x * 32 + sl];
        unsigned g4 = egoU[(size_t)c4.x * 32 + sl];
        unsigned g5 = egoU[(size_t)c5.x * 32 + sl];
        unsigned g6 = egoU[(size_t)c6.x * 32 + sl];
        unsigned g7 = egoU[(size_t)c7.x * 32 + sl];
        float w0 = __builtin_bit_cast(float, c0.y);
        float w1 = __builtin_bit_cast(float, c1.y);
        float w2 = __builtin_bit_cast(float, c2.y);
        float w3 = __builtin_bit_cast(float, c3.y);
        float w4 = __builtin_bit_cast(float, c4.y);
        float w5 = __builtin_bit_cast(float, c5.y);
        float w6 = __builtin_bit_cast(float, c6.y);
        float w7 = __builtin_bit_cast(float, c7.y);
        l0 = fmaf(w0, bf2f((unsigned short)(g0 & 0xffffu)), l0);
        h0 = fmaf(w0, bf2f((unsigned short)(g0 >> 16)), h0);
        l1 = fmaf(w1, bf2f((unsigned short)(g1 & 0xffffu)), l1);
        h1 = fmaf(w1, bf2f((unsigned short)(g1 >> 16)), h1);
        l2 = fmaf(w2, bf2f((unsigned short)(g2 & 0xffffu)), l2);
        h2 = fmaf(w2, bf2f((unsigned short)(g2 >> 16)), h2);
        l3 = fmaf(w3, bf2f((unsigned short)(g3 & 0xffffu)), l3);
        h3 = fmaf(w3, bf2f((unsigned short)(g3 >> 16)), h3);
        l0 = fmaf(w4, bf2f((unsigned short)(g4 & 0xffffu)), l0);
        h0 = fmaf(w4, bf2f((unsigned short)(g4 >> 16)), h0);
        l1 = fmaf(w5, bf2f((unsigned short)(g5 & 0xffffu)), l1);
        h1 = fmaf(w5, bf2f((unsigned short)(g5 >> 16)), h1);
        l2 = fmaf(w6, bf2f((unsigned short)(g6 & 0xffffu)), l2);
        h2 = fmaf(w6, bf2f((unsigned short)(g6 >> 16)), h2);
        l3 = fmaf(w7, bf2f((unsigned short)(g7 & 0xffffu)), l3);
        h3 = fmaf(w7, bf2f((unsigned short)(g7 >> 16)), h3);
    }
    if (k + 7 < e) {
        int2 c0 = sce[k + 0 + half];
        int2 c1 = sce[k + 2 + half];
        int2 c2 = sce[k + 4 + half];
        int2 c3 = sce[k + 6 + half];
        unsigned g0 = egoU[(size_t)c0.x * 32 + sl];
        unsigned g1 = egoU[(size_t)c1.x * 32 + sl];
        unsigned g2 = egoU[(size_t)c2.x * 32 + sl];
        unsigned g3 = egoU[(size_t)c3.x * 32 + sl];
        float w0 = __builtin_bit_cast(float, c0.y);
        float w1 = __builtin_bit_cast(float, c1.y);
        float w2 = __builtin_bit_cast(float, c2.y);
        float w3 = __builtin_bit_cast(float, c3.y);
        l0 = fmaf(w0, bf2f((unsigned short)(g0 & 0xffffu)), l0);
        h0 = fmaf(w0, bf2f((unsigned short)(g0 >> 16)), h0);
        l1 = fmaf(w1, bf2f((unsigned short)(g1 & 0xffffu)), l1);
        h1 = fmaf(w1, bf2f((unsigned short)(g1 >> 16)), h1);
        l2 = fmaf(w2, bf2f((unsigned short)(g2 & 0xffffu)), l2);
        h2 = fmaf(w2, bf2f((unsigned short)(g2 >> 16)), h2);
        l3 = fmaf(w3, bf2f((unsigned short)(g3 & 0xffffu)), l3);
        h3 = fmaf(w3, bf2f((unsigned short)(g3 >> 16)), h3);
        k += 8;
    }
    if (k + 3 < e) {
        int2 c0 = sce[k + 0 + half];
        int2 c1 = sce[k + 2 + half];
        unsigned g0 = egoU[(size_t)c0.x * 32 + sl];
        unsigned g1 = egoU[(size_t)c1.x * 32 + sl];
        float w0 = __builtin_bit_cast(float, c0.y);
        float w1 = __builtin_bit_cast(float, c1.y);
        l0 = fmaf(w0, bf2f((unsigned short)(g0 & 0xffffu)), l0);
        h0 = fmaf(w0, bf2f((unsigned short)(g0 >> 16)), h0);
        l1 = fmaf(w1, bf2f((unsigned short)(g1 & 0xffffu)), l1);
        h1 = fmaf(w1, bf2f((unsigned short)(g1 >> 16)), h1);
        k += 4;
    }
    for (; k < e; k += 2) {
        int idx = k + half;
        bool ok = idx < e;
        int2 c = sce[ok ? idx : (e - 1)];
        float w = ok ? __builtin_bit_cast(float, c.y) : 0.f;
        unsigned g = egoU[(size_t)c.x * 32 + sl];
        l0 = fmaf(w, bf2f((unsigned short)(g & 0xffffu)), l0);
        h0 = fmaf(w, bf2f((unsigned short)(g >> 16)), h0);
    }
    float lo = (l0 + l1) + (l2 + l3);
    float hi = (h0 + h1) + (h2 + h3);
    lo += __shfl_xor(lo, 32, 64);
    hi += __shfl_xor(hi, 32, 64);
    if (half == 0) {
        unsigned outp = (unsigned)f2bf(lo) | ((unsigned)f2bf(hi) << 16);
        ((unsigned*)side_bf)[(size_t)r * 32 + sl] = outp;
    }
}

// ---------------- dense via MFMA bf16, all-bf16 I/O, in-place ego -------
__global__ __launch_bounds__(256) void gemm_dense_kernel(
    unsigned short* __restrict__ ego,            // bf16 in/out
    const unsigned short* __restrict__ side_bf,
    const unsigned short* __restrict__ BT, const float* __restrict__ b1,
    const float* __restrict__ b2, float* __restrict__ nrm) {
    __shared__ unsigned short A_lds[64][136];  // 272B row stride, 16B aligned
    const int tid  = threadIdx.x;
    const int lane = tid & 63, wm = tid >> 6;
    const int m = lane & 15, g = lane >> 4;
    const int base = blockIdx.x * 64;

    bfrag8 b[4][4];
#pragma unroll
    for (int nt = 0; nt < 4; ++nt)
#pragma unroll
        for (int kt = 0; kt < 4; ++kt)
            b[nt][kt] =
                *(const bfrag8*)(BT + (nt * 16 + m) * 128 + kt * 32 + g * 8);

    float bias[4];
#pragma unroll
    for (int nt = 0; nt < 4; ++nt)
        bias[nt] = b1[nt * 16 + m] + b2[nt * 16 + m];

    // stage A tile: sli = ego+side, pr = ego*side (all bf16, 16B loads)
#pragma unroll
    for (int it = 0; it < 2; ++it) {
        int idx = it * 256 + tid;     // 0..511
        int n = idx >> 3, c = idx & 7;  // row, 8-dim chunk
        int node = base + n;
        uint4 ev = make_uint4(0, 0, 0, 0), sv = make_uint4(0, 0, 0, 0);
        if (node < N_NODES) {
            ev = ((const uint4*)ego)[(size_t)node * 8 + c];
            sv = ((const uint4*)side_bf)[(size_t)node * 8 + c];
        }
        unsigned evu[4] = {ev.x, ev.y, ev.z, ev.w};
        unsigned svu[4] = {sv.x, sv.y, sv.z, sv.w};
        unsigned q[4], pq[4];
#pragma unroll
        for (int j = 0; j < 4; ++j) {
            float e0 = bf2f((unsigned short)(evu[j] & 0xffffu));
            float e1 = bf2f((unsigned short)(evu[j] >> 16));
            float s0 = bf2f((unsigned short)(svu[j] & 0xffffu));
            float s1 = bf2f((unsigned short)(svu[j] >> 16));
            q[j]  = f2bf(e0 + s0) | ((unsigned)f2bf(e1 + s1) << 16);
            pq[j] = f2bf(e0 * s0) | ((unsigned)f2bf(e1 * s1) << 16);
        }
        *(uint4*)&A_lds[n][c * 8]      = make_uint4(q[0], q[1], q[2], q[3]);
        *(uint4*)&A_lds[n][64 + c * 8] = make_uint4(pq[0], pq[1], pq[2], pq[3]);
    }
    __syncthreads();

    bfrag8 a[4];
#pragma unroll
    for (int kt = 0; kt < 4; ++kt)
        a[kt] = *(const bfrag8*)&A_lds[wm * 16 + m][kt * 32 + g * 8];

    vf4 acc[4];
#pragma unroll
    for (int nt = 0; nt < 4; ++nt) acc[nt] = (vf4){0.f, 0.f, 0.f, 0.f};
#pragma unroll
    for (int kt = 0; kt < 4; ++kt)
#pragma unroll
        for (int nt = 0; nt < 4; ++nt)
            acc[nt] = __builtin_amdgcn_mfma_f32_16x16x32_bf16(
                a[kt], b[nt][kt], acc[nt], 0, 0, 0);

    float o[4][4];
    float sq[4] = {0.f, 0.f, 0.f, 0.f};
#pragma unroll
    for (int nt = 0; nt < 4; ++nt)
#pragma unroll
        for (int r = 0; r < 4; ++r) {
            float v = acc[nt][r] + bias[nt];
            v = (v >= 0.f) ? v : 0.01f * v;
            o[nt][r] = v;
            sq[r] += v * v;
        }
#pragma unroll
    for (int r = 0; r < 4; ++r)
#pragma unroll
        for (int off = 1; off < 16; off <<= 1)
            sq[r] += __shfl_xor(sq[r], off, 64);  // reduce over m (same rows)

#pragma unroll
    for (int r = 0; r < 4; ++r) {
        int row = base + wm * 16 + g * 4 + r;  // C/D: row=(lane>>4)*4+reg
        if (row < N_NODES) {
#pragma unroll
            for (int nt = 0; nt < 4; ++nt)
                ego[(size_t)row * 64 + nt * 16 + m] = f2bf(o[nt][r]);
            if (m == 0) nrm[row] = fmaxf(sqrtf(sq[r]), 1e-12f);
        }
    }
}

// ---------------- batch accumulation over one 64-dim concat segment ------
__global__ __launch_bounds__(256) void batch_kernel(
    const unsigned short* __restrict__ ego_bf, const float* __restrict__ nrm,
    int use_nrm, const int* __restrict__ u, const int* __restrict__ pi,
    const int* __restrict__ ni, float* __restrict__ dot_ui,
    float* __restrict__ dot_uj, float* __restrict__ l2b) {
    const int lane = threadIdx.x & 63;
    int b = (blockIdx.x * blockDim.x + threadIdx.x) >> 6;
    if (b >= BATCH) return;
    int un = u[b];
    int pn = N_USERS + pi[b];
    int nn = N_USERS + ni[b];
    float fu = bf2f(ego_bf[(size_t)un * EMB + lane]);
    float fp = bf2f(ego_bf[(size_t)pn * EMB + lane]);
    float fn_ = bf2f(ego_bf[(size_t)nn * EMB + lane]);
    if (use_nrm) {
        fu /= nrm[un];
        fp /= nrm[pn];
        fn_ /= nrm[nn];
    }
    float dup = fu * fp;
    float dun = fu * fn_;
    float l2  = fu * fu + fp * fp + fn_ * fn_;
#pragma unroll
    for (int off = 32; off; off >>= 1) {
        dup += __shfl_xor(dup, off, 64);
        dun += __shfl_xor(dun, off, 64);
        l2  += __shfl_xor(l2, off, 64);
    }
    if (lane == 0) {
        dot_ui[b] += dup;
        dot_uj[b] += dun;
        l2b[b]    += l2;
    }
}

// ---------------- final scalar reduce ----------------
__global__ __launch_bounds__(256) void final_kernel(
    const float* __restrict__ dot_ui, const float* __restrict__ dot_uj,
    const float* __restrict__ l2b, float* __restrict__ out) {
    __shared__ float sl[256], s2[256];
    float accL = 0.f, acc2 = 0.f;
    for (int b = threadIdx.x; b < BATCH; b += 256) {
        float x = dot_ui[b] - dot_uj[b];
        float sp = (x > 0.f) ? log1pf(expf(-x)) : (-x + log1pf(expf(x)));
        accL += sp;
        acc2 += l2b[b];
    }
    sl[threadIdx.x] = accL;
    s2[threadIdx.x] = acc2;
    __syncthreads();
    for (int off = 128; off; off >>= 1) {
        if (threadIdx.x < off) {
            sl[threadIdx.x] += sl[threadIdx.x + off];
            s2[threadIdx.x] += s2[threadIdx.x + off];
        }
        __syncthreads();
    }
    if (threadIdx.x == 0)
        out[0] = sl[0] / (float)BATCH + REG * (s2[0] * 0.5f / (float)BATCH);
}

extern "C" void kernel_launch(void* const* d_in, const int* in_sizes, int n_in,
                              void* d_out, int out_size, void* d_ws,
                              size_t ws_size, hipStream_t stream) {
    const int*   adj_row  = (const int*)d_in[0];
    const int*   adj_col  = (const int*)d_in[1];
    const float* adj_val  = (const float*)d_in[2];
    const float* user_emb = (const float*)d_in[3];
    const float* item_emb = (const float*)d_in[4];
    const float* W1       = (const float*)d_in[5];
    const float* b1       = (const float*)d_in[6];
    const float* W2       = (const float*)d_in[7];
    const float* b2       = (const float*)d_in[8];
    const int*   u        = (const int*)d_in[9];
    const int*   ii       = (const int*)d_in[10];
    const int*   jj       = (const int*)d_in[11];

    char* p = (char*)d_ws;
    auto alloc = [&](size_t bytes) {
        char* q = p;
        p += (bytes + 255) & ~(size_t)255;
        return q;
    };
    unsigned short* ego    = (unsigned short*)alloc((size_t)N_NODES * EMB * 2);
    unsigned short* side_bf= (unsigned short*)alloc((size_t)N_NODES * EMB * 2);
    int2*           sce    = (int2*)alloc((size_t)NNZ * 8);
    int2*           stage  = (int2*)alloc((size_t)NNZ * 8);
    int*            rp     = (int*)alloc((size_t)(N_NODES + 1) * 4);
    int*            bcur   = (int*)alloc((size_t)NB_BUCKET * 4);
    int*            cnt    = (int*)alloc((size_t)N_NODES * 4);
    int*            bsum   = (int*)alloc(128 * 4);
    float*          nrm    = (float*)alloc((size_t)N_NODES * 4);
    float*          dot_ui = (float*)alloc((size_t)BATCH * 4);
    float*          dot_uj = (float*)alloc((size_t)BATCH * 4);
    float*          l2b    = (float*)alloc((size_t)BATCH * 4);
    unsigned short* BT     = (unsigned short*)alloc((size_t)NLAYERS * 8192 * 2);

    hipMemsetAsync(dot_ui, 0, BATCH * sizeof(float), stream);
    hipMemsetAsync(dot_uj, 0, BATCH * sizeof(float), stream);
    hipMemsetAsync(l2b, 0, BATCH * sizeof(float), stream);
    hipMemsetAsync(cnt, 0, N_NODES * sizeof(int), stream);

    prep_w_kernel<<<(NLAYERS * 8192 + 255) / 256, 256, 0, stream>>>(W1, W2, BT);

    // ---- build CSR (once; shared by all 3 layers) ----
    hist_kernel<<<(NNZ + 255) / 256, 256, 0, stream>>>(adj_row, cnt);
    scan1_kernel<<<SCAN_NB, SCAN_BS, 0, stream>>>(cnt, rp, bsum);
    scan2_kernel<<<1, 128, 0, stream>>>(bsum);
    scan3_kernel<<<(N_NODES + 255) / 256, 256, 0, stream>>>(rp, bsum, bcur);
    binscatter_kernel<<<BIN_NB, 256, 0, stream>>>(adj_row, adj_col, adj_val,
                                                  bcur, stage);
    bucket_place_kernel<<<NB_BUCKET, 256, 0, stream>>>(stage, rp, sce);

    init_ego_kernel<<<2048, 256, 0, stream>>>((const float4*)user_emb,
                                              (const float4*)item_emb,
                                              (ushort4*)ego);

    batch_kernel<<<BATCH / 4, 256, 0, stream>>>(ego, nrm, 0, u, ii, jj,
                                                dot_ui, dot_uj, l2b);

    for (int k = 0; k < NLAYERS; ++k) {
        spmm_csr_kernel<<<(N_NODES * 64 + 255) / 256, 256, 0, stream>>>(
            rp, sce, ego, side_bf);
        gemm_dense_kernel<<<NTILES, 256, 0, stream>>>(
            ego, side_bf, BT + (size_t)k * 8192, b1 + (size_t)k * EMB,
            b2 + (size_t)k * EMB, nrm);
        batch_kernel<<<BATCH / 4, 256, 0, stream>>>(ego, nrm, 1, u, ii, jj,
                                                    dot_ui, dot_uj, l2b);
    }

    final_kernel<<<1, 256, 0, stream>>>(dot_ui, dot_uj, l2b, (float*)d_out);
}

// Round 11
// 476.750 us; speedup vs baseline: 1.1722x; 1.1722x over previous
//
#include <hip/hip_runtime.h>

#define N_USERS 100000
#define N_ITEMS 50000
#define N_NODES 150000
#define NNZ     2400000
#define EMB     64
#define NLAYERS 3
#define BATCH   16384
#define REG     1e-5f

#define NTILES ((N_NODES + 63) / 64)  // 2344

#define ROWS_PER_BUCKET 256
#define NB_BUCKET ((N_NODES + ROWS_PER_BUCKET - 1) / ROWS_PER_BUCKET)  // 586
#define BIN_CHUNK 8192
#define BIN_NB ((NNZ + BIN_CHUNK - 1) / BIN_CHUNK)  // 293

typedef __attribute__((ext_vector_type(8))) short bfrag8;  // 8 bf16 (4 VGPRs)
typedef __attribute__((ext_vector_type(4))) float vf4;     // 4 f32 acc

__device__ inline unsigned short f2bf(float x) {  // f32 -> bf16 RTN-even
    unsigned int u = __builtin_bit_cast(unsigned int, x);
    return (unsigned short)((u + 0x7fffu + ((u >> 16) & 1u)) >> 16);
}
__device__ inline float bf2f(unsigned short h) {
    unsigned int u = ((unsigned int)h) << 16;
    return __builtin_bit_cast(float, u);
}

// ---------------- init: ego_bf = bf16(concat(user_emb, item_emb)) -------
__global__ void init_ego_kernel(const float4* __restrict__ ue,
                                const float4* __restrict__ ie,
                                ushort4* __restrict__ ego_bf) {
    const int n4u = N_USERS * (EMB / 4);
    const int n4  = N_NODES * (EMB / 4);
    for (int t = blockIdx.x * blockDim.x + threadIdx.x; t < n4;
         t += gridDim.x * blockDim.x) {
        float4 v = (t < n4u) ? ue[t] : ie[t - n4u];
        ushort4 h;
        h.x = f2bf(v.x); h.y = f2bf(v.y); h.z = f2bf(v.z); h.w = f2bf(v.w);
        ego_bf[t] = h;
    }
}

// ---------------- prep: BT[layer][j][k] = bf16([W1;W2][k][j]) ------------
__global__ __launch_bounds__(256) void prep_w_kernel(
    const float* __restrict__ W1, const float* __restrict__ W2,
    unsigned short* __restrict__ BT) {
    int idx = blockIdx.x * blockDim.x + threadIdx.x;
    if (idx >= NLAYERS * 64 * 128) return;
    int l = idx / 8192;
    int rem = idx - l * 8192;
    int j = rem >> 7;        // output dim (row of BT)
    int k = rem & 127;       // concat-K
    float w = (k < 64) ? W1[l * 4096 + k * 64 + j]
                       : W2[l * 4096 + (k - 64) * 64 + j];
    BT[idx] = f2bf(w);
}

// ---------------- bucket histogram: 586 bins via LDS ----------------
__global__ __launch_bounds__(256) void bhist_kernel(const int* __restrict__ row,
                                                    int* __restrict__ bcnt) {
    __shared__ int h[NB_BUCKET];
    const int t = threadIdx.x;
    for (int b = t; b < NB_BUCKET; b += 256) h[b] = 0;
    __syncthreads();
    const int s = blockIdx.x * BIN_CHUNK;
    const int e = min(s + BIN_CHUNK, NNZ);
    for (int i = s + t; i < e; i += 256) atomicAdd(&h[row[i] >> 8], 1);
    __syncthreads();
    for (int b = t; b < NB_BUCKET; b += 256)
        if (h[b]) atomicAdd(&bcnt[b], h[b]);
}

// ---------------- bucket scan: bases + cursors (single block) -----------
__global__ __launch_bounds__(1024) void bscan_kernel(
    const int* __restrict__ bcnt, int* __restrict__ bbase,
    int* __restrict__ bcur) {
    __shared__ int sc[1024];
    const int t = threadIdx.x;
    int v = (t < NB_BUCKET) ? bcnt[t] : 0;
    sc[t] = v;
    __syncthreads();
    int x = v;
    for (int off = 1; off < 1024; off <<= 1) {
        int y = (t >= off) ? sc[t - off] : 0;
        __syncthreads();
        x += y;
        sc[t] = x;
        __syncthreads();
    }
    if (t < NB_BUCKET) {
        int base = x - v;  // exclusive
        bbase[t] = base;
        bcur[t]  = base;
    }
    if (t == 0) bbase[NB_BUCKET] = NNZ;
}

// ---------------- pass A: bucket-binned scatter ----------------
__global__ __launch_bounds__(256) void binscatter_kernel(
    const int* __restrict__ row, const int* __restrict__ col,
    const float* __restrict__ val, int* __restrict__ bucket_cursor,
    int2* __restrict__ stage) {
    __shared__ int hist[NB_BUCKET];
    __shared__ int wbase[NB_BUCKET];
    const int t = threadIdx.x;
    const int s = blockIdx.x * BIN_CHUNK;
    const int e = min(s + BIN_CHUNK, NNZ);

    for (int b = t; b < NB_BUCKET; b += 256) hist[b] = 0;
    __syncthreads();
    for (int i = s + t; i < e; i += 256)
        atomicAdd(&hist[row[i] >> 8], 1);
    __syncthreads();
    for (int b = t; b < NB_BUCKET; b += 256) {
        int c = hist[b];
        wbase[b] = c ? atomicAdd(&bucket_cursor[b], c) : 0;
        hist[b] = 0;  // reuse as local cursor
    }
    __syncthreads();
    for (int i = s + t; i < e; i += 256) {
        int r = row[i];
        int b = r >> 8;
        int off = atomicAdd(&hist[b], 1);
        stage[wbase[b] + off] =
            make_int2(col[i] | ((r & 255) << 18),
                      __builtin_bit_cast(int, val[i]));
    }
}

// ---------------- pass B: row-count + scan + CSR placement --------------
// One block per bucket: LDS 256-bin row histogram of the staged segment,
// in-block exclusive scan -> writes rp for its rows, then places edges.
__global__ __launch_bounds__(256) void bucket_place_kernel(
    const int2* __restrict__ stage, const int* __restrict__ bbase,
    int* __restrict__ rp, int2* __restrict__ sce) {
    __shared__ int cnt[ROWS_PER_BUCKET];
    __shared__ int sc[ROWS_PER_BUCKET];
    __shared__ int cur[ROWS_PER_BUCKET];
    const int b = blockIdx.x;
    const int t = threadIdx.x;
    const int row0 = b * ROWS_PER_BUCKET;
    const int B0 = bbase[b];
    const int B1 = bbase[b + 1];
    cnt[t] = 0;
    __syncthreads();
    for (int i = B0 + t; i < B1; i += 256)
        atomicAdd(&cnt[(stage[i].x >> 18) & 255], 1);
    __syncthreads();
    int v = cnt[t];
    sc[t] = v;
    __syncthreads();
    int x = v;
    for (int off = 1; off < 256; off <<= 1) {
        int y = (t >= off) ? sc[t - off] : 0;
        __syncthreads();
        x += y;
        sc[t] = x;
        __syncthreads();
    }
    int excl = x - v;
    int row = row0 + t;
    if (row <= N_NODES) rp[row] = B0 + excl;   // row==N_NODES -> rp=NNZ
    cur[t] = B0 + excl;
    __syncthreads();
    for (int i = B0 + t; i < B1; i += 256) {
        int2 pk = stage[i];
        int rl = (pk.x >> 18) & 255;
        int pos = atomicAdd(&cur[rl], 1);
        sce[pos] = make_int2(pk.x & 0x3FFFF, pk.y);
    }
}

// ---------------- CSR SpMM: half-wave per edge, 2 dims/lane -------------
__global__ __launch_bounds__(256) void spmm_csr_kernel(
    const int* __restrict__ rp, const int2* __restrict__ sce,
    const unsigned short* __restrict__ ego_bf,
    unsigned short* __restrict__ side_bf) {
    const int lane = threadIdx.x & 63;
    const int half = lane >> 5;   // which edge of the pair
    const int sl   = lane & 31;   // dim-pair index (dims 2*sl, 2*sl+1)
    int r = (blockIdx.x * blockDim.x + threadIdx.x) >> 6;
    if (r >= N_NODES) return;
    const unsigned* egoU = (const unsigned*)ego_bf;  // row stride 32 uints
    int s = rp[r], e = rp[r + 1];
    float l0 = 0.f, l1 = 0.f, l2 = 0.f, l3 = 0.f;
    float h0 = 0.f, h1 = 0.f, h2 = 0.f, h3 = 0.f;
    int k = s;
    for (; k + 15 < e; k += 16) {
        int2 c0 = sce[k + 0 + half];
        int2 c1 = sce[k + 2 + half];
        int2 c2 = sce[k + 4 + half];
        int2 c3 = sce[k + 6 + half];
        int2 c4 = sce[k + 8 + half];
        int2 c5 = sce[k + 10 + half];
        int2 c6 = sce[k + 12 + half];
        int2 c7 = sce[k + 14 + half];
        unsigned g0 = egoU[(size_t)c0.x * 32 + sl];
        unsigned g1 = egoU[(size_t)c1.x * 32 + sl];
        unsigned g2 = egoU[(size_t)c2.x * 32 + sl];
        unsigned g3 = egoU[(size_t)c3.x * 32 + sl];
        unsigned g4 = egoU[(size_t)c4.x * 32 + sl];
        unsigned g5 = egoU[(size_t)c5.x * 32 + sl];
        unsigned g6 = egoU[(size_t)c6.x * 32 + sl];
        unsigned g7 = egoU[(size_t)c7.x * 32 + sl];
        float w0 = __builtin_bit_cast(float, c0.y);
        float w1 = __builtin_bit_cast(float, c1.y);
        float w2 = __builtin_bit_cast(float, c2.y);
        float w3 = __builtin_bit_cast(float, c3.y);
        float w4 = __builtin_bit_cast(float, c4.y);
        float w5 = __builtin_bit_cast(float, c5.y);
        float w6 = __builtin_bit_cast(float, c6.y);
        float w7 = __builtin_bit_cast(float, c7.y);
        l0 = fmaf(w0, bf2f((unsigned short)(g0 & 0xffffu)), l0);
        h0 = fmaf(w0, bf2f((unsigned short)(g0 >> 16)), h0);
        l1 = fmaf(w1, bf2f((unsigned short)(g1 & 0xffffu)), l1);
        h1 = fmaf(w1, bf2f((unsigned short)(g1 >> 16)), h1);
        l2 = fmaf(w2, bf2f((unsigned short)(g2 & 0xffffu)), l2);
        h2 = fmaf(w2, bf2f((unsigned short)(g2 >> 16)), h2);
        l3 = fmaf(w3, bf2f((unsigned short)(g3 & 0xffffu)), l3);
        h3 = fmaf(w3, bf2f((unsigned short)(g3 >> 16)), h3);
        l0 = fmaf(w4, bf2f((unsigned short)(g4 & 0xffffu)), l0);
        h0 = fmaf(w4, bf2f((unsigned short)(g4 >> 16)), h0);
        l1 = fmaf(w5, bf2f((unsigned short)(g5 & 0xffffu)), l1);
        h1 = fmaf(w5, bf2f((unsigned short)(g5 >> 16)), h1);
        l2 = fmaf(w6, bf2f((unsigned short)(g6 & 0xffffu)), l2);
        h2 = fmaf(w6, bf2f((unsigned short)(g6 >> 16)), h2);
        l3 = fmaf(w7, bf2f((unsigned short)(g7 & 0xffffu)), l3);
        h3 = fmaf(w7, bf2f((unsigned short)(g7 >> 16)), h3);
    }
    if (k + 7 < e) {
        int2 c0 = sce[k + 0 + half];
        int2 c1 = sce[k + 2 + half];
        int2 c2 = sce[k + 4 + half];
        int2 c3 = sce[k + 6 + half];
        unsigned g0 = egoU[(size_t)c0.x * 32 + sl];
        unsigned g1 = egoU[(size_t)c1.x * 32 + sl];
        unsigned g2 = egoU[(size_t)c2.x * 32 + sl];
        unsigned g3 = egoU[(size_t)c3.x * 32 + sl];
        float w0 = __builtin_bit_cast(float, c0.y);
        float w1 = __builtin_bit_cast(float, c1.y);
        float w2 = __builtin_bit_cast(float, c2.y);
        float w3 = __builtin_bit_cast(float, c3.y);
        l0 = fmaf(w0, bf2f((unsigned short)(g0 & 0xffffu)), l0);
        h0 = fmaf(w0, bf2f((unsigned short)(g0 >> 16)), h0);
        l1 = fmaf(w1, bf2f((unsigned short)(g1 & 0xffffu)), l1);
        h1 = fmaf(w1, bf2f((unsigned short)(g1 >> 16)), h1);
        l2 = fmaf(w2, bf2f((unsigned short)(g2 & 0xffffu)), l2);
        h2 = fmaf(w2, bf2f((unsigned short)(g2 >> 16)), h2);
        l3 = fmaf(w3, bf2f((unsigned short)(g3 & 0xffffu)), l3);
        h3 = fmaf(w3, bf2f((unsigned short)(g3 >> 16)), h3);
        k += 8;
    }
    if (k + 3 < e) {
        int2 c0 = sce[k + 0 + half];
        int2 c1 = sce[k + 2 + half];
        unsigned g0 = egoU[(size_t)c0.x * 32 + sl];
        unsigned g1 = egoU[(size_t)c1.x * 32 + sl];
        float w0 = __builtin_bit_cast(float, c0.y);
        float w1 = __builtin_bit_cast(float, c1.y);
        l0 = fmaf(w0, bf2f((unsigned short)(g0 & 0xffffu)), l0);
        h0 = fmaf(w0, bf2f((unsigned short)(g0 >> 16)), h0);
        l1 = fmaf(w1, bf2f((unsigned short)(g1 & 0xffffu)), l1);
        h1 = fmaf(w1, bf2f((unsigned short)(g1 >> 16)), h1);
        k += 4;
    }
    for (; k < e; k += 2) {
        int idx = k + half;
        bool ok = idx < e;
        int2 c = sce[ok ? idx : (e - 1)];
        float w = ok ? __builtin_bit_cast(float, c.y) : 0.f;
        unsigned g = egoU[(size_t)c.x * 32 + sl];
        l0 = fmaf(w, bf2f((unsigned short)(g & 0xffffu)), l0);
        h0 = fmaf(w, bf2f((unsigned short)(g >> 16)), h0);
    }
    float lo = (l0 + l1) + (l2 + l3);
    float hi = (h0 + h1) + (h2 + h3);
    lo += __shfl_xor(lo, 32, 64);
    hi += __shfl_xor(hi, 32, 64);
    if (half == 0) {
        unsigned outp = (unsigned)f2bf(lo) | ((unsigned)f2bf(hi) << 16);
        ((unsigned*)side_bf)[(size_t)r * 32 + sl] = outp;
    }
}

// ---------------- dense via MFMA bf16, all-bf16 I/O, in-place ego -------
__global__ __launch_bounds__(256) void gemm_dense_kernel(
    unsigned short* __restrict__ ego,            // bf16 in/out
    const unsigned short* __restrict__ side_bf,
    const unsigned short* __restrict__ BT, const float* __restrict__ b1,
    const float* __restrict__ b2, float* __restrict__ nrm) {
    __shared__ unsigned short A_lds[64][136];  // 272B row stride, 16B aligned
    const int tid  = threadIdx.x;
    const int lane = tid & 63, wm = tid >> 6;
    const int m = lane & 15, g = lane >> 4;
    const int base = blockIdx.x * 64;

    bfrag8 b[4][4];
#pragma unroll
    for (int nt = 0; nt < 4; ++nt)
#pragma unroll
        for (int kt = 0; kt < 4; ++kt)
            b[nt][kt] =
                *(const bfrag8*)(BT + (nt * 16 + m) * 128 + kt * 32 + g * 8);

    float bias[4];
#pragma unroll
    for (int nt = 0; nt < 4; ++nt)
        bias[nt] = b1[nt * 16 + m] + b2[nt * 16 + m];

    // stage A tile: sli = ego+side, pr = ego*side (all bf16, 16B loads)
#pragma unroll
    for (int it = 0; it < 2; ++it) {
        int idx = it * 256 + tid;     // 0..511
        int n = idx >> 3, c = idx & 7;  // row, 8-dim chunk
        int node = base + n;
        uint4 ev = make_uint4(0, 0, 0, 0), sv = make_uint4(0, 0, 0, 0);
        if (node < N_NODES) {
            ev = ((const uint4*)ego)[(size_t)node * 8 + c];
            sv = ((const uint4*)side_bf)[(size_t)node * 8 + c];
        }
        unsigned evu[4] = {ev.x, ev.y, ev.z, ev.w};
        unsigned svu[4] = {sv.x, sv.y, sv.z, sv.w};
        unsigned q[4], pq[4];
#pragma unroll
        for (int j = 0; j < 4; ++j) {
            float e0 = bf2f((unsigned short)(evu[j] & 0xffffu));
            float e1 = bf2f((unsigned short)(evu[j] >> 16));
            float s0 = bf2f((unsigned short)(svu[j] & 0xffffu));
            float s1 = bf2f((unsigned short)(svu[j] >> 16));
            q[j]  = f2bf(e0 + s0) | ((unsigned)f2bf(e1 + s1) << 16);
            pq[j] = f2bf(e0 * s0) | ((unsigned)f2bf(e1 * s1) << 16);
        }
        *(uint4*)&A_lds[n][c * 8]      = make_uint4(q[0], q[1], q[2], q[3]);
        *(uint4*)&A_lds[n][64 + c * 8] = make_uint4(pq[0], pq[1], pq[2], pq[3]);
    }
    __syncthreads();

    bfrag8 a[4];
#pragma unroll
    for (int kt = 0; kt < 4; ++kt)
        a[kt] = *(const bfrag8*)&A_lds[wm * 16 + m][kt * 32 + g * 8];

    vf4 acc[4];
#pragma unroll
    for (int nt = 0; nt < 4; ++nt) acc[nt] = (vf4){0.f, 0.f, 0.f, 0.f};
#pragma unroll
    for (int kt = 0; kt < 4; ++kt)
#pragma unroll
        for (int nt = 0; nt < 4; ++nt)
            acc[nt] = __builtin_amdgcn_mfma_f32_16x16x32_bf16(
                a[kt], b[nt][kt], acc[nt], 0, 0, 0);

    float o[4][4];
    float sq[4] = {0.f, 0.f, 0.f, 0.f};
#pragma unroll
    for (int nt = 0; nt < 4; ++nt)
#pragma unroll
        for (int r = 0; r < 4; ++r) {
            float v = acc[nt][r] + bias[nt];
            v = (v >= 0.f) ? v : 0.01f * v;
            o[nt][r] = v;
            sq[r] += v * v;
        }
#pragma unroll
    for (int r = 0; r < 4; ++r)
#pragma unroll
        for (int off = 1; off < 16; off <<= 1)
            sq[r] += __shfl_xor(sq[r], off, 64);  // reduce over m (same rows)

#pragma unroll
    for (int r = 0; r < 4; ++r) {
        int row = base + wm * 16 + g * 4 + r;  // C/D: row=(lane>>4)*4+reg
        if (row < N_NODES) {
#pragma unroll
            for (int nt = 0; nt < 4; ++nt)
                ego[(size_t)row * 64 + nt * 16 + m] = f2bf(o[nt][r]);
            if (m == 0) nrm[row] = fmaxf(sqrtf(sq[r]), 1e-12f);
        }
    }
}

// ---------------- batch accumulation over one 64-dim concat segment ------
__global__ __launch_bounds__(256) void batch_kernel(
    const unsigned short* __restrict__ ego_bf, const float* __restrict__ nrm,
    int use_nrm, const int* __restrict__ u, const int* __restrict__ pi,
    const int* __restrict__ ni, float* __restrict__ dot_ui,
    float* __restrict__ dot_uj, float* __restrict__ l2b) {
    const int lane = threadIdx.x & 63;
    int b = (blockIdx.x * blockDim.x + threadIdx.x) >> 6;
    if (b >= BATCH) return;
    int un = u[b];
    int pn = N_USERS + pi[b];
    int nn = N_USERS + ni[b];
    float fu = bf2f(ego_bf[(size_t)un * EMB + lane]);
    float fp = bf2f(ego_bf[(size_t)pn * EMB + lane]);
    float fn_ = bf2f(ego_bf[(size_t)nn * EMB + lane]);
    if (use_nrm) {
        fu /= nrm[un];
        fp /= nrm[pn];
        fn_ /= nrm[nn];
    }
    float dup = fu * fp;
    float dun = fu * fn_;
    float l2  = fu * fu + fp * fp + fn_ * fn_;
#pragma unroll
    for (int off = 32; off; off >>= 1) {
        dup += __shfl_xor(dup, off, 64);
        dun += __shfl_xor(dun, off, 64);
        l2  += __shfl_xor(l2, off, 64);
    }
    if (lane == 0) {
        dot_ui[b] += dup;
        dot_uj[b] += dun;
        l2b[b]    += l2;
    }
}

// ---------------- final scalar reduce ----------------
__global__ __launch_bounds__(256) void final_kernel(
    const float* __restrict__ dot_ui, const float* __restrict__ dot_uj,
    const float* __restrict__ l2b, float* __restrict__ out) {
    __shared__ float sl[256], s2[256];
    float accL = 0.f, acc2 = 0.f;
    for (int b = threadIdx.x; b < BATCH; b += 256) {
        float x = dot_ui[b] - dot_uj[b];
        float sp = (x > 0.f) ? log1pf(expf(-x)) : (-x + log1pf(expf(x)));
        accL += sp;
        acc2 += l2b[b];
    }
    sl[threadIdx.x] = accL;
    s2[threadIdx.x] = acc2;
    __syncthreads();
    for (int off = 128; off; off >>= 1) {
        if (threadIdx.x < off) {
            sl[threadIdx.x] += sl[threadIdx.x + off];
            s2[threadIdx.x] += s2[threadIdx.x + off];
        }
        __syncthreads();
    }
    if (threadIdx.x == 0)
        out[0] = sl[0] / (float)BATCH + REG * (s2[0] * 0.5f / (float)BATCH);
}

extern "C" void kernel_launch(void* const* d_in, const int* in_sizes, int n_in,
                              void* d_out, int out_size, void* d_ws,
                              size_t ws_size, hipStream_t stream) {
    const int*   adj_row  = (const int*)d_in[0];
    const int*   adj_col  = (const int*)d_in[1];
    const float* adj_val  = (const float*)d_in[2];
    const float* user_emb = (const float*)d_in[3];
    const float* item_emb = (const float*)d_in[4];
    const float* W1       = (const float*)d_in[5];
    const float* b1       = (const float*)d_in[6];
    const float* W2       = (const float*)d_in[7];
    const float* b2       = (const float*)d_in[8];
    const int*   u        = (const int*)d_in[9];
    const int*   ii       = (const int*)d_in[10];
    const int*   jj       = (const int*)d_in[11];

    char* p = (char*)d_ws;
    auto alloc = [&](size_t bytes) {
        char* q = p;
        p += (bytes + 255) & ~(size_t)255;
        return q;
    };
    unsigned short* ego    = (unsigned short*)alloc((size_t)N_NODES * EMB * 2);
    unsigned short* side_bf= (unsigned short*)alloc((size_t)N_NODES * EMB * 2);
    int2*           sce    = (int2*)alloc((size_t)NNZ * 8);
    int2*           stage  = (int2*)alloc((size_t)NNZ * 8);
    int*            rp     = (int*)alloc((size_t)(N_NODES + 1) * 4);
    int*            bcnt   = (int*)alloc((size_t)NB_BUCKET * 4);
    int*            bbase  = (int*)alloc((size_t)(NB_BUCKET + 1) * 4);
    int*            bcur   = (int*)alloc((size_t)NB_BUCKET * 4);
    float*          nrm    = (float*)alloc((size_t)N_NODES * 4);
    float*          dot_ui = (float*)alloc((size_t)BATCH * 4);
    float*          dot_uj = (float*)alloc((size_t)BATCH * 4);
    float*          l2b    = (float*)alloc((size_t)BATCH * 4);
    unsigned short* BT     = (unsigned short*)alloc((size_t)NLAYERS * 8192 * 2);

    hipMemsetAsync(dot_ui, 0, BATCH * sizeof(float), stream);
    hipMemsetAsync(dot_uj, 0, BATCH * sizeof(float), stream);
    hipMemsetAsync(l2b, 0, BATCH * sizeof(float), stream);
    hipMemsetAsync(bcnt, 0, NB_BUCKET * sizeof(int), stream);

    prep_w_kernel<<<(NLAYERS * 8192 + 255) / 256, 256, 0, stream>>>(W1, W2, BT);

    // ---- build CSR (once; shared by all 3 layers) ----
    bhist_kernel<<<BIN_NB, 256, 0, stream>>>(adj_row, bcnt);
    bscan_kernel<<<1, 1024, 0, stream>>>(bcnt, bbase, bcur);
    binscatter_kernel<<<BIN_NB, 256, 0, stream>>>(adj_row, adj_col, adj_val,
                                                  bcur, stage);
    bucket_place_kernel<<<NB_BUCKET, 256, 0, stream>>>(stage, bbase, rp, sce);

    init_ego_kernel<<<2048, 256, 0, stream>>>((const float4*)user_emb,
                                              (const float4*)item_emb,
                                              (ushort4*)ego);

    batch_kernel<<<BATCH / 4, 256, 0, stream>>>(ego, nrm, 0, u, ii, jj,
                                                dot_ui, dot_uj, l2b);

    for (int k = 0; k < NLAYERS; ++k) {
        spmm_csr_kernel<<<(N_NODES * 64 + 255) / 256, 256, 0, stream>>>(
            rp, sce, ego, side_bf);
        gemm_dense_kernel<<<NTILES, 256, 0, stream>>>(
            ego, side_bf, BT + (size_t)k * 8192, b1 + (size_t)k * EMB,
            b2 + (size_t)k * EMB, nrm);
        batch_kernel<<<BATCH / 4, 256, 0, stream>>>(ego, nrm, 1, u, ii, jj,
                                                    dot_ui, dot_uj, l2b);
    }

    final_kernel<<<1, 256, 0, stream>>>(dot_ui, dot_uj, l2b, (float*)d_out);
}

// Round 12
// 456.855 us; speedup vs baseline: 1.2233x; 1.0435x over previous
//
#include <hip/hip_runtime.h>

#define N_USERS 100000
#define N_ITEMS 50000
#define N_NODES 150000
#define NNZ     2400000
#define EMB     64
#define NLAYERS 3
#define BATCH   16384
#define REG     1e-5f

#define NTILES ((N_NODES + 63) / 64)  // 2344

#define ROWS_PER_BUCKET 256
#define NB_BUCKET ((N_NODES + ROWS_PER_BUCKET - 1) / ROWS_PER_BUCKET)  // 586
#define BIN_CHUNK 4096
#define BIN_NB ((NNZ + BIN_CHUNK - 1) / BIN_CHUNK)  // 586
#define BCAP 6144   // per-bucket staging capacity: mean 4096, sigma 64

typedef __attribute__((ext_vector_type(8))) short bfrag8;  // 8 bf16 (4 VGPRs)
typedef __attribute__((ext_vector_type(4))) float vf4;     // 4 f32 acc

__device__ inline unsigned short f2bf(float x) {  // f32 -> bf16 RTN-even
    unsigned int u = __builtin_bit_cast(unsigned int, x);
    return (unsigned short)((u + 0x7fffu + ((u >> 16) & 1u)) >> 16);
}
__device__ inline float bf2f(unsigned short h) {
    unsigned int u = ((unsigned int)h) << 16;
    return __builtin_bit_cast(float, u);
}

// ---------------- init: ego_bf = bf16(concat(user_emb, item_emb)) -------
__global__ void init_ego_kernel(const float4* __restrict__ ue,
                                const float4* __restrict__ ie,
                                ushort4* __restrict__ ego_bf) {
    const int n4u = N_USERS * (EMB / 4);
    const int n4  = N_NODES * (EMB / 4);
    for (int t = blockIdx.x * blockDim.x + threadIdx.x; t < n4;
         t += gridDim.x * blockDim.x) {
        float4 v = (t < n4u) ? ue[t] : ie[t - n4u];
        ushort4 h;
        h.x = f2bf(v.x); h.y = f2bf(v.y); h.z = f2bf(v.z); h.w = f2bf(v.w);
        ego_bf[t] = h;
    }
}

// ---------------- prep: BT[layer][j][k] = bf16([W1;W2][k][j]) ------------
__global__ __launch_bounds__(256) void prep_w_kernel(
    const float* __restrict__ W1, const float* __restrict__ W2,
    unsigned short* __restrict__ BT) {
    int idx = blockIdx.x * blockDim.x + threadIdx.x;
    if (idx >= NLAYERS * 64 * 128) return;
    int l = idx / 8192;
    int rem = idx - l * 8192;
    int j = rem >> 7;        // output dim (row of BT)
    int k = rem & 127;       // concat-K
    float w = (k < 64) ? W1[l * 4096 + k * 64 + j]
                       : W2[l * 4096 + (k - 64) * 64 + j];
    BT[idx] = f2bf(w);
}

// ---------------- pass A: bucket-binned scatter (fixed-cap regions) -----
// 1024 thr/block, 586 blocks => ~32 waves/CU (was 4.7 at 256thr/293blk).
// stage[b*BCAP + off]; per-(block,bucket) contiguous ranges via LDS hist.
__global__ __launch_bounds__(1024) void binscatter_kernel(
    const int* __restrict__ row, const int* __restrict__ col,
    const float* __restrict__ val, int* __restrict__ bcnt,
    int2* __restrict__ stage) {
    __shared__ int hist[NB_BUCKET];
    __shared__ int wbase[NB_BUCKET];
    const int t = threadIdx.x;
    const int s = blockIdx.x * BIN_CHUNK;
    const int e = min(s + BIN_CHUNK, NNZ);

    for (int b = t; b < NB_BUCKET; b += 1024) hist[b] = 0;
    __syncthreads();
    for (int i = s + t; i < e; i += 1024)
        atomicAdd(&hist[row[i] >> 8], 1);
    __syncthreads();
    for (int b = t; b < NB_BUCKET; b += 1024) {
        int c = hist[b];
        wbase[b] = c ? atomicAdd(&bcnt[b], c) : 0;
        hist[b] = 0;  // reuse as local cursor
    }
    __syncthreads();
    for (int i = s + t; i < e; i += 1024) {
        int r = row[i];
        int b = r >> 8;
        int off = atomicAdd(&hist[b], 1);
        stage[(size_t)b * BCAP + wbase[b] + off] =
            make_int2(col[i] | ((r & 255) << 18),
                      __builtin_bit_cast(int, val[i]));
    }
}

// ---------------- bucket scan: CSR bases from measured counts -----------
__global__ __launch_bounds__(1024) void bscan_kernel(
    const int* __restrict__ bcnt, int* __restrict__ bbase) {
    __shared__ int sc[1024];
    const int t = threadIdx.x;
    int v = (t < NB_BUCKET) ? bcnt[t] : 0;
    sc[t] = v;
    __syncthreads();
    int x = v;
    for (int off = 1; off < 1024; off <<= 1) {
        int y = (t >= off) ? sc[t - off] : 0;
        __syncthreads();
        x += y;
        sc[t] = x;
        __syncthreads();
    }
    if (t < NB_BUCKET) bbase[t] = x - v;  // exclusive
    if (t == 0) bbase[NB_BUCKET] = NNZ;
}

// ---------------- pass B: row-count + scan + CSR placement --------------
__global__ __launch_bounds__(256) void bucket_place_kernel(
    const int2* __restrict__ stage, const int* __restrict__ bcnt,
    const int* __restrict__ bbase, int* __restrict__ rp,
    int2* __restrict__ sce) {
    __shared__ int cnt[ROWS_PER_BUCKET];
    __shared__ int sc[ROWS_PER_BUCKET];
    __shared__ int cur[ROWS_PER_BUCKET];
    const int b = blockIdx.x;
    const int t = threadIdx.x;
    const int row0 = b * ROWS_PER_BUCKET;
    const size_t S0 = (size_t)b * BCAP;
    const int ne = bcnt[b];
    const int B0 = bbase[b];
    cnt[t] = 0;
    __syncthreads();
    for (int i = t; i < ne; i += 256)
        atomicAdd(&cnt[(stage[S0 + i].x >> 18) & 255], 1);
    __syncthreads();
    int v = cnt[t];
    sc[t] = v;
    __syncthreads();
    int x = v;
    for (int off = 1; off < 256; off <<= 1) {
        int y = (t >= off) ? sc[t - off] : 0;
        __syncthreads();
        x += y;
        sc[t] = x;
        __syncthreads();
    }
    int excl = x - v;
    int row = row0 + t;
    if (row <= N_NODES) rp[row] = B0 + excl;   // row==N_NODES -> rp=NNZ
    cur[t] = B0 + excl;
    __syncthreads();
    for (int i = t; i < ne; i += 256) {
        int2 pk = stage[S0 + i];
        int rl = (pk.x >> 18) & 255;
        int pos = atomicAdd(&cur[rl], 1);
        sce[pos] = make_int2(pk.x & 0x3FFFF, pk.y);
    }
}

// ---------------- CSR SpMM: half-wave per edge, 2 dims/lane -------------
__global__ __launch_bounds__(256) void spmm_csr_kernel(
    const int* __restrict__ rp, const int2* __restrict__ sce,
    const unsigned short* __restrict__ ego_bf,
    unsigned short* __restrict__ side_bf) {
    const int lane = threadIdx.x & 63;
    const int half = lane >> 5;   // which edge of the pair
    const int sl   = lane & 31;   // dim-pair index (dims 2*sl, 2*sl+1)
    int r = (blockIdx.x * blockDim.x + threadIdx.x) >> 6;
    if (r >= N_NODES) return;
    const unsigned* egoU = (const unsigned*)ego_bf;  // row stride 32 uints
    int s = rp[r], e = rp[r + 1];
    float l0 = 0.f, l1 = 0.f, l2 = 0.f, l3 = 0.f;
    float h0 = 0.f, h1 = 0.f, h2 = 0.f, h3 = 0.f;
    int k = s;
    for (; k + 15 < e; k += 16) {
        int2 c0 = sce[k + 0 + half];
        int2 c1 = sce[k + 2 + half];
        int2 c2 = sce[k + 4 + half];
        int2 c3 = sce[k + 6 + half];
        int2 c4 = sce[k + 8 + half];
        int2 c5 = sce[k + 10 + half];
        int2 c6 = sce[k + 12 + half];
        int2 c7 = sce[k + 14 + half];
        unsigned g0 = egoU[(size_t)c0.x * 32 + sl];
        unsigned g1 = egoU[(size_t)c1.x * 32 + sl];
        unsigned g2 = egoU[(size_t)c2.x * 32 + sl];
        unsigned g3 = egoU[(size_t)c3.x * 32 + sl];
        unsigned g4 = egoU[(size_t)c4.x * 32 + sl];
        unsigned g5 = egoU[(size_t)c5.x * 32 + sl];
        unsigned g6 = egoU[(size_t)c6.x * 32 + sl];
        unsigned g7 = egoU[(size_t)c7.x * 32 + sl];
        float w0 = __builtin_bit_cast(float, c0.y);
        float w1 = __builtin_bit_cast(float, c1.y);
        float w2 = __builtin_bit_cast(float, c2.y);
        float w3 = __builtin_bit_cast(float, c3.y);
        float w4 = __builtin_bit_cast(float, c4.y);
        float w5 = __builtin_bit_cast(float, c5.y);
        float w6 = __builtin_bit_cast(float, c6.y);
        float w7 = __builtin_bit_cast(float, c7.y);
        l0 = fmaf(w0, bf2f((unsigned short)(g0 & 0xffffu)), l0);
        h0 = fmaf(w0, bf2f((unsigned short)(g0 >> 16)), h0);
        l1 = fmaf(w1, bf2f((unsigned short)(g1 & 0xffffu)), l1);
        h1 = fmaf(w1, bf2f((unsigned short)(g1 >> 16)), h1);
        l2 = fmaf(w2, bf2f((unsigned short)(g2 & 0xffffu)), l2);
        h2 = fmaf(w2, bf2f((unsigned short)(g2 >> 16)), h2);
        l3 = fmaf(w3, bf2f((unsigned short)(g3 & 0xffffu)), l3);
        h3 = fmaf(w3, bf2f((unsigned short)(g3 >> 16)), h3);
        l0 = fmaf(w4, bf2f((unsigned short)(g4 & 0xffffu)), l0);
        h0 = fmaf(w4, bf2f((unsigned short)(g4 >> 16)), h0);
        l1 = fmaf(w5, bf2f((unsigned short)(g5 & 0xffffu)), l1);
        h1 = fmaf(w5, bf2f((unsigned short)(g5 >> 16)), h1);
        l2 = fmaf(w6, bf2f((unsigned short)(g6 & 0xffffu)), l2);
        h2 = fmaf(w6, bf2f((unsigned short)(g6 >> 16)), h2);
        l3 = fmaf(w7, bf2f((unsigned short)(g7 & 0xffffu)), l3);
        h3 = fmaf(w7, bf2f((unsigned short)(g7 >> 16)), h3);
    }
    if (k + 7 < e) {
        int2 c0 = sce[k + 0 + half];
        int2 c1 = sce[k + 2 + half];
        int2 c2 = sce[k + 4 + half];
        int2 c3 = sce[k + 6 + half];
        unsigned g0 = egoU[(size_t)c0.x * 32 + sl];
        unsigned g1 = egoU[(size_t)c1.x * 32 + sl];
        unsigned g2 = egoU[(size_t)c2.x * 32 + sl];
        unsigned g3 = egoU[(size_t)c3.x * 32 + sl];
        float w0 = __builtin_bit_cast(float, c0.y);
        float w1 = __builtin_bit_cast(float, c1.y);
        float w2 = __builtin_bit_cast(float, c2.y);
        float w3 = __builtin_bit_cast(float, c3.y);
        l0 = fmaf(w0, bf2f((unsigned short)(g0 & 0xffffu)), l0);
        h0 = fmaf(w0, bf2f((unsigned short)(g0 >> 16)), h0);
        l1 = fmaf(w1, bf2f((unsigned short)(g1 & 0xffffu)), l1);
        h1 = fmaf(w1, bf2f((unsigned short)(g1 >> 16)), h1);
        l2 = fmaf(w2, bf2f((unsigned short)(g2 & 0xffffu)), l2);
        h2 = fmaf(w2, bf2f((unsigned short)(g2 >> 16)), h2);
        l3 = fmaf(w3, bf2f((unsigned short)(g3 & 0xffffu)), l3);
        h3 = fmaf(w3, bf2f((unsigned short)(g3 >> 16)), h3);
        k += 8;
    }
    if (k + 3 < e) {
        int2 c0 = sce[k + 0 + half];
        int2 c1 = sce[k + 2 + half];
        unsigned g0 = egoU[(size_t)c0.x * 32 + sl];
        unsigned g1 = egoU[(size_t)c1.x * 32 + sl];
        float w0 = __builtin_bit_cast(float, c0.y);
        float w1 = __builtin_bit_cast(float, c1.y);
        l0 = fmaf(w0, bf2f((unsigned short)(g0 & 0xffffu)), l0);
        h0 = fmaf(w0, bf2f((unsigned short)(g0 >> 16)), h0);
        l1 = fmaf(w1, bf2f((unsigned short)(g1 & 0xffffu)), l1);
        h1 = fmaf(w1, bf2f((unsigned short)(g1 >> 16)), h1);
        k += 4;
    }
    for (; k < e; k += 2) {
        int idx = k + half;
        bool ok = idx < e;
        int2 c = sce[ok ? idx : (e - 1)];
        float w = ok ? __builtin_bit_cast(float, c.y) : 0.f;
        unsigned g = egoU[(size_t)c.x * 32 + sl];
        l0 = fmaf(w, bf2f((unsigned short)(g & 0xffffu)), l0);
        h0 = fmaf(w, bf2f((unsigned short)(g >> 16)), h0);
    }
    float lo = (l0 + l1) + (l2 + l3);
    float hi = (h0 + h1) + (h2 + h3);
    lo += __shfl_xor(lo, 32, 64);
    hi += __shfl_xor(hi, 32, 64);
    if (half == 0) {
        unsigned outp = (unsigned)f2bf(lo) | ((unsigned)f2bf(hi) << 16);
        ((unsigned*)side_bf)[(size_t)r * 32 + sl] = outp;
    }
}

// ---------------- dense via MFMA bf16, all-bf16 I/O, in-place ego -------
__global__ __launch_bounds__(256) void gemm_dense_kernel(
    unsigned short* __restrict__ ego,            // bf16 in/out
    const unsigned short* __restrict__ side_bf,
    const unsigned short* __restrict__ BT, const float* __restrict__ b1,
    const float* __restrict__ b2, float* __restrict__ nrm) {
    __shared__ unsigned short A_lds[64][136];  // 272B row stride, 16B aligned
    const int tid  = threadIdx.x;
    const int lane = tid & 63, wm = tid >> 6;
    const int m = lane & 15, g = lane >> 4;
    const int base = blockIdx.x * 64;

    bfrag8 b[4][4];
#pragma unroll
    for (int nt = 0; nt < 4; ++nt)
#pragma unroll
        for (int kt = 0; kt < 4; ++kt)
            b[nt][kt] =
                *(const bfrag8*)(BT + (nt * 16 + m) * 128 + kt * 32 + g * 8);

    float bias[4];
#pragma unroll
    for (int nt = 0; nt < 4; ++nt)
        bias[nt] = b1[nt * 16 + m] + b2[nt * 16 + m];

    // stage A tile: sli = ego+side, pr = ego*side (all bf16, 16B loads)
#pragma unroll
    for (int it = 0; it < 2; ++it) {
        int idx = it * 256 + tid;     // 0..511
        int n = idx >> 3, c = idx & 7;  // row, 8-dim chunk
        int node = base + n;
        uint4 ev = make_uint4(0, 0, 0, 0), sv = make_uint4(0, 0, 0, 0);
        if (node < N_NODES) {
            ev = ((const uint4*)ego)[(size_t)node * 8 + c];
            sv = ((const uint4*)side_bf)[(size_t)node * 8 + c];
        }
        unsigned evu[4] = {ev.x, ev.y, ev.z, ev.w};
        unsigned svu[4] = {sv.x, sv.y, sv.z, sv.w};
        unsigned q[4], pq[4];
#pragma unroll
        for (int j = 0; j < 4; ++j) {
            float e0 = bf2f((unsigned short)(evu[j] & 0xffffu));
            float e1 = bf2f((unsigned short)(evu[j] >> 16));
            float s0 = bf2f((unsigned short)(svu[j] & 0xffffu));
            float s1 = bf2f((unsigned short)(svu[j] >> 16));
            q[j]  = f2bf(e0 + s0) | ((unsigned)f2bf(e1 + s1) << 16);
            pq[j] = f2bf(e0 * s0) | ((unsigned)f2bf(e1 * s1) << 16);
        }
        *(uint4*)&A_lds[n][c * 8]      = make_uint4(q[0], q[1], q[2], q[3]);
        *(uint4*)&A_lds[n][64 + c * 8] = make_uint4(pq[0], pq[1], pq[2], pq[3]);
    }
    __syncthreads();

    bfrag8 a[4];
#pragma unroll
    for (int kt = 0; kt < 4; ++kt)
        a[kt] = *(const bfrag8*)&A_lds[wm * 16 + m][kt * 32 + g * 8];

    vf4 acc[4];
#pragma unroll
    for (int nt = 0; nt < 4; ++nt) acc[nt] = (vf4){0.f, 0.f, 0.f, 0.f};
#pragma unroll
    for (int kt = 0; kt < 4; ++kt)
#pragma unroll
        for (int nt = 0; nt < 4; ++nt)
            acc[nt] = __builtin_amdgcn_mfma_f32_16x16x32_bf16(
                a[kt], b[nt][kt], acc[nt], 0, 0, 0);

    float o[4][4];
    float sq[4] = {0.f, 0.f, 0.f, 0.f};
#pragma unroll
    for (int nt = 0; nt < 4; ++nt)
#pragma unroll
        for (int r = 0; r < 4; ++r) {
            float v = acc[nt][r] + bias[nt];
            v = (v >= 0.f) ? v : 0.01f * v;
            o[nt][r] = v;
            sq[r] += v * v;
        }
#pragma unroll
    for (int r = 0; r < 4; ++r)
#pragma unroll
        for (int off = 1; off < 16; off <<= 1)
            sq[r] += __shfl_xor(sq[r], off, 64);  // reduce over m (same rows)

#pragma unroll
    for (int r = 0; r < 4; ++r) {
        int row = base + wm * 16 + g * 4 + r;  // C/D: row=(lane>>4)*4+reg
        if (row < N_NODES) {
#pragma unroll
            for (int nt = 0; nt < 4; ++nt)
                ego[(size_t)row * 64 + nt * 16 + m] = f2bf(o[nt][r]);
            if (m == 0) nrm[row] = fmaxf(sqrtf(sq[r]), 1e-12f);
        }
    }
}

// ---------------- batch accumulation over one 64-dim concat segment ------
__global__ __launch_bounds__(256) void batch_kernel(
    const unsigned short* __restrict__ ego_bf, const float* __restrict__ nrm,
    int use_nrm, const int* __restrict__ u, const int* __restrict__ pi,
    const int* __restrict__ ni, float* __restrict__ dot_ui,
    float* __restrict__ dot_uj, float* __restrict__ l2b) {
    const int lane = threadIdx.x & 63;
    int b = (blockIdx.x * blockDim.x + threadIdx.x) >> 6;
    if (b >= BATCH) return;
    int un = u[b];
    int pn = N_USERS + pi[b];
    int nn = N_USERS + ni[b];
    float fu = bf2f(ego_bf[(size_t)un * EMB + lane]);
    float fp = bf2f(ego_bf[(size_t)pn * EMB + lane]);
    float fn_ = bf2f(ego_bf[(size_t)nn * EMB + lane]);
    if (use_nrm) {
        fu /= nrm[un];
        fp /= nrm[pn];
        fn_ /= nrm[nn];
    }
    float dup = fu * fp;
    float dun = fu * fn_;
    float l2  = fu * fu + fp * fp + fn_ * fn_;
#pragma unroll
    for (int off = 32; off; off >>= 1) {
        dup += __shfl_xor(dup, off, 64);
        dun += __shfl_xor(dun, off, 64);
        l2  += __shfl_xor(l2, off, 64);
    }
    if (lane == 0) {
        dot_ui[b] += dup;
        dot_uj[b] += dun;
        l2b[b]    += l2;
    }
}

// ---------------- final scalar reduce ----------------
__global__ __launch_bounds__(256) void final_kernel(
    const float* __restrict__ dot_ui, const float* __restrict__ dot_uj,
    const float* __restrict__ l2b, float* __restrict__ out) {
    __shared__ float sl[256], s2[256];
    float accL = 0.f, acc2 = 0.f;
    for (int b = threadIdx.x; b < BATCH; b += 256) {
        float x = dot_ui[b] - dot_uj[b];
        float sp = (x > 0.f) ? log1pf(expf(-x)) : (-x + log1pf(expf(x)));
        accL += sp;
        acc2 += l2b[b];
    }
    sl[threadIdx.x] = accL;
    s2[threadIdx.x] = acc2;
    __syncthreads();
    for (int off = 128; off; off >>= 1) {
        if (threadIdx.x < off) {
            sl[threadIdx.x] += sl[threadIdx.x + off];
            s2[threadIdx.x] += s2[threadIdx.x + off];
        }
        __syncthreads();
    }
    if (threadIdx.x == 0)
        out[0] = sl[0] / (float)BATCH + REG * (s2[0] * 0.5f / (float)BATCH);
}

extern "C" void kernel_launch(void* const* d_in, const int* in_sizes, int n_in,
                              void* d_out, int out_size, void* d_ws,
                              size_t ws_size, hipStream_t stream) {
    const int*   adj_row  = (const int*)d_in[0];
    const int*   adj_col  = (const int*)d_in[1];
    const float* adj_val  = (const float*)d_in[2];
    const float* user_emb = (const float*)d_in[3];
    const float* item_emb = (const float*)d_in[4];
    const float* W1       = (const float*)d_in[5];
    const float* b1       = (const float*)d_in[6];
    const float* W2       = (const float*)d_in[7];
    const float* b2       = (const float*)d_in[8];
    const int*   u        = (const int*)d_in[9];
    const int*   ii       = (const int*)d_in[10];
    const int*   jj       = (const int*)d_in[11];

    char* p = (char*)d_ws;
    auto alloc = [&](size_t bytes) {
        char* q = p;
        p += (bytes + 255) & ~(size_t)255;
        return q;
    };
    unsigned short* ego    = (unsigned short*)alloc((size_t)N_NODES * EMB * 2);
    unsigned short* side_bf= (unsigned short*)alloc((size_t)N_NODES * EMB * 2);
    int2*           sce    = (int2*)alloc((size_t)NNZ * 8);
    int2*           stage  = (int2*)alloc((size_t)NB_BUCKET * BCAP * 8);
    int*            rp     = (int*)alloc((size_t)(N_NODES + 1) * 4);
    int*            bcnt   = (int*)alloc((size_t)NB_BUCKET * 4);
    int*            bbase  = (int*)alloc((size_t)(NB_BUCKET + 1) * 4);
    float*          nrm    = (float*)alloc((size_t)N_NODES * 4);
    float*          dot_ui = (float*)alloc((size_t)BATCH * 4);
    float*          dot_uj = (float*)alloc((size_t)BATCH * 4);
    float*          l2b    = (float*)alloc((size_t)BATCH * 4);
    unsigned short* BT     = (unsigned short*)alloc((size_t)NLAYERS * 8192 * 2);

    hipMemsetAsync(dot_ui, 0, BATCH * sizeof(float), stream);
    hipMemsetAsync(dot_uj, 0, BATCH * sizeof(float), stream);
    hipMemsetAsync(l2b, 0, BATCH * sizeof(float), stream);
    hipMemsetAsync(bcnt, 0, NB_BUCKET * sizeof(int), stream);

    prep_w_kernel<<<(NLAYERS * 8192 + 255) / 256, 256, 0, stream>>>(W1, W2, BT);

    // ---- build CSR (once; shared by all 3 layers) ----
    binscatter_kernel<<<BIN_NB, 1024, 0, stream>>>(adj_row, adj_col, adj_val,
                                                   bcnt, stage);
    bscan_kernel<<<1, 1024, 0, stream>>>(bcnt, bbase);
    bucket_place_kernel<<<NB_BUCKET, 256, 0, stream>>>(stage, bcnt, bbase, rp,
                                                       sce);

    init_ego_kernel<<<2048, 256, 0, stream>>>((const float4*)user_emb,
                                              (const float4*)item_emb,
                                              (ushort4*)ego);

    batch_kernel<<<BATCH / 4, 256, 0, stream>>>(ego, nrm, 0, u, ii, jj,
                                                dot_ui, dot_uj, l2b);

    for (int k = 0; k < NLAYERS; ++k) {
        spmm_csr_kernel<<<(N_NODES * 64 + 255) / 256, 256, 0, stream>>>(
            rp, sce, ego, side_bf);
        gemm_dense_kernel<<<NTILES, 256, 0, stream>>>(
            ego, side_bf, BT + (size_t)k * 8192, b1 + (size_t)k * EMB,
            b2 + (size_t)k * EMB, nrm);
        batch_kernel<<<BATCH / 4, 256, 0, stream>>>(ego, nrm, 1, u, ii, jj,
                                                    dot_ui, dot_uj, l2b);
    }

    final_kernel<<<1, 256, 0, stream>>>(dot_ui, dot_uj, l2b, (float*)d_out);
}